// Round 3
// baseline (512.043 us; speedup 1.0000x reference)
//
#include <hip/hip_runtime.h>
#include <math.h>

#define B_ 64
#define T_ 1024
#define D_ 512
#define U_ 1024

typedef __bf16 bf16x8 __attribute__((ext_vector_type(8)));
typedef float f32x16 __attribute__((ext_vector_type(16)));
typedef unsigned int u32;

__device__ __forceinline__ float fast_tanh(float x) {
    float ax = fabsf(x);
    float e = __expf(2.0f * ax);
    float r = 1.0f - __fdividef(2.0f, e + 1.0f);
    return copysignf(r, x);
}

__device__ __forceinline__ u32 f2bf_pk(float lo, float hi) {
    u32 a = __float_as_uint(lo) + 0x8000u;
    u32 b = __float_as_uint(hi) + 0x8000u;
    return (a >> 16) | (b & 0xffff0000u);
}

// K_prep: blocks [0,256): W1 [D][U] fp32 -> W1F in MFMA-fragment order:
//   frag=(ut*16+kt)*2+ks holds B-frag for u-tile ut (32 u), k=kt*32+ks*16;
//   slot (frag,lane) = 8 bf16: u=ut*32+(lane&31), k0=kt*32+ks*16+(lane>>5)*8.
// blocks [256,512): ph[b][u] = hidden·W2 + W2_b + W1_b; also zero out_ctx
// for the atomic accumulation in ctx_kernel.
__global__ __launch_bounds__(256) void prep_kernel(
    const float* __restrict__ W1, const float* __restrict__ hidden,
    const float* __restrict__ W2, const float* __restrict__ W2b,
    const float* __restrict__ W1b,
    unsigned short* __restrict__ W1F, float* __restrict__ ph,
    float* __restrict__ ctx0) {
    if (blockIdx.x < 256) {
        const int gid  = blockIdx.x * 256 + threadIdx.x;  // 0..65535
        const int lane = gid & 63;
        const int frag = gid >> 6;                        // 0..1023
        const int ks = frag & 1;
        const int kt = (frag >> 1) & 15;
        const int ut = frag >> 5;
        const int u  = ut * 32 + (lane & 31);
        const int k0 = kt * 32 + ks * 16 + (lane >> 5) * 8;
        float f[8];
#pragma unroll
        for (int j = 0; j < 8; ++j) f[j] = W1[(size_t)(k0 + j) * U_ + u];
        uint4 w;
        w.x = f2bf_pk(f[0], f[1]);
        w.y = f2bf_pk(f[2], f[3]);
        w.z = f2bf_pk(f[4], f[5]);
        w.w = f2bf_pk(f[6], f[7]);
        *(uint4*)&W1F[(size_t)gid * 8] = w;
    } else {
        const int bx = blockIdx.x - 256;
        const int zi = bx * 256 + (int)threadIdx.x;
        if (zi < B_ * D_) ctx0[zi] = 0.f;
        const int u  = (bx & 3) * 256 + threadIdx.x;
        const int b  = bx >> 2;
        const float* h = hidden + b * D_;
        float acc = 0.f;
#pragma unroll 8
        for (int d = 0; d < D_; ++d) acc = fmaf(h[d], W2[(size_t)d * U_ + u], acc);
        ph[b * U_ + u] = acc + W2b[u] + W1b[u];
    }
}

// K2: fused bf16 32x32x16-MFMA GEMM + tanh + V-dot.
// One block per (b, 64-t tile); both u-halves computed sequentially against a
// single staged A tile. ONE barrier (post-stage). Cross-u reduction: per-wave
// multi-value shfl tree (31 shfls); uh=0's reduced scalar is HELD IN A REG and
// summed with uh=1's, then a final shfl gathers values into IDENTITY lane
// order (lane l holds row l) so each wave issues ONE ascending-contiguous
// 256 B store. (Round-2's permuted-lane store was counted as 1M separate
// 128 B line transactions -> 134 MB HBM writes; ascending order fixes it,
// cf. round-0's 512 KB with a tid-ordered store.)
__global__ __launch_bounds__(512, 4) void logits_mfma_kernel(
    const float* __restrict__ feat,          // [B,T,D] fp32
    const unsigned short* __restrict__ W1F,  // fragment-order bf16
    const float* __restrict__ ph,            // [B,U] biases folded
    const float* __restrict__ Vw,            // [U]
    float* __restrict__ lpart) {             // [8][B][T] partials
    __shared__ __align__(16) char As[65536];  // 16 panels x 64 rows x 64 B

    const int tid  = threadIdx.x;
    const int tt   = blockIdx.x;        // 0..15
    const int b    = blockIdx.y;
    const int t0   = tt * 64;
    const int lane = tid & 63;
    const int widx = tid >> 6;
    const int l31 = lane & 31, g = lane >> 5;

    // ---- stage A once: feat[b, t0..t0+64, :] fp32 -> bf16 swizzled panels ----
    {
        const int r  = tid >> 3;       // 0..63
        const int s0 = tid & 7;
        const float* src = feat + ((size_t)(b * T_ + t0 + r)) * D_;
        const int xr = (r >> 2) & 3;
#pragma unroll
        for (int i = 0; i < 8; ++i) {
            const int s = s0 + 8 * i;            // 16B slot in row
            const float4 v0 = *(const float4*)(src + s * 8);
            const float4 v1 = *(const float4*)(src + s * 8 + 4);
            uint4 w;
            w.x = f2bf_pk(v0.x, v0.y);
            w.y = f2bf_pk(v0.z, v0.w);
            w.z = f2bf_pk(v1.x, v1.y);
            w.w = f2bf_pk(v1.z, v1.w);
            const int panel = s >> 2, q = s & 3;
            *(uint4*)&As[panel * 4096 + r * 64 + (q ^ xr) * 16] = w;
        }
    }
    __syncthreads();   // the ONLY barrier in this kernel

    // B frag bases for the wave's u-strip in each u-half (u0 = uh*512+widx*64)
    const char* bb0 = (const char*)W1F + (size_t)(widx * 2) * 32768 + lane * 16;
    const char* bb1 = bb0 + (size_t)16 * 32768;

    f32x16 acc[2][2];
    bf16x8 b0[4], b1[4];

    auto loadB = [&](const char* bb, bf16x8* dst, int kt) {
#pragma unroll
        for (int nt = 0; nt < 2; ++nt)
#pragma unroll
            for (int ks = 0; ks < 2; ++ks)
                dst[nt * 2 + ks] =
                    *(const bf16x8*)(bb + nt * 32768 + (kt * 2 + ks) * 1024);
    };

    auto computeStep = [&](int kt, const bf16x8* bfr) {
        bf16x8 af[2][2];   // [ks][mt]
#pragma unroll
        for (int ks = 0; ks < 2; ++ks)
#pragma unroll
            for (int mt = 0; mt < 2; ++mt) {
                const int rr = mt * 32 + l31;
                const int q  = (2 * ks + g) ^ ((rr >> 2) & 3);
                af[ks][mt] = *(const bf16x8*)&As[kt * 4096 + rr * 64 + q * 16];
            }
        __builtin_amdgcn_s_setprio(1);
#pragma unroll
        for (int ks = 0; ks < 2; ++ks)
#pragma unroll
            for (int mt = 0; mt < 2; ++mt)
#pragma unroll
                for (int nt = 0; nt < 2; ++nt)
                    acc[mt][nt] = __builtin_amdgcn_mfma_f32_32x32x16_bf16(
                        af[ks][mt], bfr[nt * 2 + ks], acc[mt][nt], 0, 0, 0);
        __builtin_amdgcn_s_setprio(0);
    };

    float vres = 0.f;   // running sum over both u-halves (per final row)

    loadB(bb0, b0, 0);
#pragma unroll
    for (int uh = 0; uh < 2; ++uh) {
        const char* bb = uh ? bb1 : bb0;
#pragma unroll
        for (int mt = 0; mt < 2; ++mt)
#pragma unroll
            for (int nt = 0; nt < 2; ++nt) acc[mt][nt] = (f32x16)(0.f);

        for (int kt = 0; kt < 16; kt += 2) {
            loadB(bb, b1, kt + 1);
            computeStep(kt, b0);
            if (kt + 2 < 16) loadB(bb, b0, kt + 2);
            computeStep(kt + 1, b1);
        }
        if (uh == 0) loadB(bb1, b0, 0);   // prefetch next pass under epilogue

        // ---- fused epilogue: tanh + V-dot into flat v[32] ----
        float v[32];
#pragma unroll
        for (int i = 0; i < 32; ++i) v[i] = 0.f;

#pragma unroll
        for (int nt = 0; nt < 2; ++nt) {
            const int u = uh * 512 + widx * 64 + nt * 32 + l31;
            const float phv = ph[b * U_ + u];
            const float vw  = Vw[u];
#pragma unroll
            for (int mt = 0; mt < 2; ++mt)
#pragma unroll
                for (int r = 0; r < 16; ++r)
                    v[mt * 16 + r] =
                        fmaf(vw, fast_tanh(acc[mt][nt][r] + phv), v[mt * 16 + r]);
        }

        // ---- multi-value tree reduce over the 32 lanes of each half ----
        // After 5 stages lane p holds the full u-strip sum for flat index
        // p&31 => row(p) = (p&3) + 8*((p>>2)&3) + 4*(p>>5) + 32*((p>>4)&1).
#pragma unroll
        for (int s = 0; s < 5; ++s) {
            const int pb = 1 << s;
            const bool hi = (l31 & pb) != 0;
#pragma unroll
            for (int j = 0; j < (16 >> s); ++j) {
                const float a = v[2 * j];
                const float c = v[2 * j + 1];
                const float keep = hi ? c : a;
                const float send = hi ? a : c;
                v[j] = keep + __shfl_xor(send, pb);
            }
        }
        vres += v[0];
    }

    // ---- identity-order gather + ONE ascending-contiguous 256 B store ----
    // Dest lane r wants the value held by lane p with row(p)=r:
    //   l31(p) = (r&3) | (((r>>3)&3)<<2) | (((r>>5)&1)<<4),  g(p) = (r>>2)&1.
    const int src = ((lane & 3) | (((lane >> 3) & 3) << 2) |
                     (((lane >> 5) & 1) << 4)) + 32 * ((lane >> 2) & 1);
    const float out = __shfl(vres, src);
    lpart[((size_t)widx) * (B_ * T_) + (size_t)b * T_ + t0 + lane] = out;
}

// K3: fused softmax + attn-write + context accumulation. grid (8 seg, B),
// block 512. Sums the 8 logit partial slots per t (stride B*T, coalesced,
// L2-hot), computes softmax, writes its own attn t-slice, then atomically
// accumulates its 128-t context contribution into out_ctx (zeroed by prep).
__global__ __launch_bounds__(512) void ctx_kernel(
    const float* __restrict__ feat, const float* __restrict__ lpart,
    float* __restrict__ attn, float* __restrict__ ctx_out) {
    const int b   = blockIdx.y;
    const int seg = blockIdx.x;
    const int tid = threadIdx.x;
    __shared__ float wls[1024];
    __shared__ float redm[8];
    __shared__ float reds[8];

    float v[2];
    float mx = -3.4e38f;
#pragma unroll
    for (int j = 0; j < 2; ++j) {
        const int t = b * T_ + tid + 512 * j;
        float s0 = 0.f, s1 = 0.f;
#pragma unroll
        for (int sl = 0; sl < 4; ++sl) {
            s0 += lpart[(size_t)(2 * sl) * (B_ * T_) + t];
            s1 += lpart[(size_t)(2 * sl + 1) * (B_ * T_) + t];
        }
        v[j] = s0 + s1;
        mx = fmaxf(mx, v[j]);
    }
#pragma unroll
    for (int off = 32; off > 0; off >>= 1) mx = fmaxf(mx, __shfl_xor(mx, off));
    if ((tid & 63) == 0) redm[tid >> 6] = mx;
    __syncthreads();
    mx = fmaxf(fmaxf(fmaxf(redm[0], redm[1]), fmaxf(redm[2], redm[3])),
               fmaxf(fmaxf(redm[4], redm[5]), fmaxf(redm[6], redm[7])));
    float s = 0.f;
#pragma unroll
    for (int j = 0; j < 2; ++j) {
        v[j] = __expf(v[j] - mx);
        s += v[j];
    }
#pragma unroll
    for (int off = 32; off > 0; off >>= 1) s += __shfl_xor(s, off);
    if ((tid & 63) == 0) reds[tid >> 6] = s;
    __syncthreads();
    s = ((reds[0] + reds[1]) + (reds[2] + reds[3])) +
        ((reds[4] + reds[5]) + (reds[6] + reds[7]));
    const float inv = 1.0f / s;
    wls[tid]       = v[0] * inv;
    wls[tid + 512] = v[1] * inv;
    __syncthreads();

    // attn write: own slice only
    if (tid < 128) attn[b * T_ + seg * 128 + tid] = wls[seg * 128 + tid];

    // context over this block's 128 t (4 quarters of 32 t)
    const int q  = tid >> 7;
    const int d4 = (tid & 127) * 4;
    const int t0 = seg * 128 + q * 32;
    const float* fb = feat + ((size_t)(b * T_ + t0)) * D_ + d4;
    const float* wb = &wls[t0];
    float4 acc = {0.f, 0.f, 0.f, 0.f};
#pragma unroll 4
    for (int t = 0; t < 32; ++t) {
        const float w  = wb[t];
        const float4 f = *(const float4*)&fb[(size_t)t * D_];
        acc.x = fmaf(w, f.x, acc.x);
        acc.y = fmaf(w, f.y, acc.y);
        acc.z = fmaf(w, f.z, acc.z);
        acc.w = fmaf(w, f.w, acc.w);
    }
    float* dst = ctx_out + b * D_ + d4;
    atomicAdd(dst + 0, acc.x);
    atomicAdd(dst + 1, acc.y);
    atomicAdd(dst + 2, acc.z);
    atomicAdd(dst + 3, acc.w);
}

extern "C" void kernel_launch(void* const* d_in, const int* in_sizes, int n_in,
                              void* d_out, int out_size, void* d_ws, size_t ws_size,
                              hipStream_t stream) {
    const float* feat   = (const float*)d_in[0];
    const float* hidden = (const float*)d_in[1];
    const float* W1w    = (const float*)d_in[2];
    const float* W1b    = (const float*)d_in[3];
    const float* W2w    = (const float*)d_in[4];
    const float* W2b    = (const float*)d_in[5];
    const float* Vw     = (const float*)d_in[6];
    // V_b cancels in softmax and doesn't affect context.

    float* out_ctx  = (float*)d_out;             // [B,D]
    float* out_attn = out_ctx + B_ * D_;         // [B,T]

    unsigned short* W1F = (unsigned short*)d_ws;             // U*D bf16 = 1 MB
    float* ph     = (float*)(W1F + (size_t)U_ * D_);         // B*U
    float* lpart  = ph + B_ * U_;                            // 8*B*T = 2 MB

    prep_kernel<<<512, 256, 0, stream>>>(W1w, hidden, W2w, W2b, W1b, W1F, ph,
                                         out_ctx);
    logits_mfma_kernel<<<dim3(16, B_), 512, 0, stream>>>(feat, W1F, ph, Vw,
                                                         lpart);
    ctx_kernel<<<dim3(8, B_), 512, 0, stream>>>(feat, lpart, out_attn, out_ctx);
}

// Round 4
// 344.215 us; speedup vs baseline: 1.4876x; 1.4876x over previous
//
#include <hip/hip_runtime.h>
#include <math.h>

#define B_ 64
#define T_ 1024
#define D_ 512
#define U_ 1024

typedef __bf16 bf16x8 __attribute__((ext_vector_type(8)));
typedef float f32x16 __attribute__((ext_vector_type(16)));
typedef unsigned int u32;

__device__ __forceinline__ float fast_tanh(float x) {
    float ax = fabsf(x);
    float e = __expf(2.0f * ax);
    float r = 1.0f - __fdividef(2.0f, e + 1.0f);
    return copysignf(r, x);
}

__device__ __forceinline__ u32 f2bf_pk(float lo, float hi) {
    u32 a = __float_as_uint(lo) + 0x8000u;
    u32 b = __float_as_uint(hi) + 0x8000u;
    return (a >> 16) | (b & 0xffff0000u);
}

// K_prep: blocks [0,256): W1 [D][U] fp32 -> W1F in MFMA-fragment order:
//   frag=(ut*16+kt)*2+ks holds B-frag for u-tile ut (32 u), k=kt*32+ks*16;
//   slot (frag,lane) = 8 bf16: u=ut*32+(lane&31), k0=kt*32+ks*16+(lane>>5)*8.
// blocks [256,512): ph[b][u] = hidden·W2 + W2_b + W1_b; also zero out_ctx
// for the atomic accumulation in ctx_kernel.
__global__ __launch_bounds__(256) void prep_kernel(
    const float* __restrict__ W1, const float* __restrict__ hidden,
    const float* __restrict__ W2, const float* __restrict__ W2b,
    const float* __restrict__ W1b,
    unsigned short* __restrict__ W1F, float* __restrict__ ph,
    float* __restrict__ ctx0) {
    if (blockIdx.x < 256) {
        const int gid  = blockIdx.x * 256 + threadIdx.x;  // 0..65535
        const int lane = gid & 63;
        const int frag = gid >> 6;                        // 0..1023
        const int ks = frag & 1;
        const int kt = (frag >> 1) & 15;
        const int ut = frag >> 5;
        const int u  = ut * 32 + (lane & 31);
        const int k0 = kt * 32 + ks * 16 + (lane >> 5) * 8;
        float f[8];
#pragma unroll
        for (int j = 0; j < 8; ++j) f[j] = W1[(size_t)(k0 + j) * U_ + u];
        uint4 w;
        w.x = f2bf_pk(f[0], f[1]);
        w.y = f2bf_pk(f[2], f[3]);
        w.z = f2bf_pk(f[4], f[5]);
        w.w = f2bf_pk(f[6], f[7]);
        *(uint4*)&W1F[(size_t)gid * 8] = w;
    } else {
        const int bx = blockIdx.x - 256;
        const int zi = bx * 256 + (int)threadIdx.x;
        if (zi < B_ * D_) ctx0[zi] = 0.f;
        const int u  = (bx & 3) * 256 + threadIdx.x;
        const int b  = bx >> 2;
        const float* h = hidden + b * D_;
        float acc = 0.f;
#pragma unroll 8
        for (int d = 0; d < D_; ++d) acc = fmaf(h[d], W2[(size_t)d * U_ + u], acc);
        ph[b * U_ + u] = acc + W2b[u] + W1b[u];
    }
}

// K2: fused bf16 32x32x16-MFMA GEMM + tanh + V-dot.
// One block per (b, 64-t tile); both u-halves computed sequentially against a
// single staged A tile. ONE barrier (post-stage). Cross-u reduction: per-wave
// multi-value shfl tree (31 shfls), then an in-loop identity-order gather shfl
// so lane l holds row l, and ONE ascending-contiguous 256 B store per wave
// per uh. NOTE register budget: launch_bounds(512,4) + 64KB LDS = 2 blocks/CU
// = 128 unified regs/wave, and we sit exactly at 64 VGPR + 64 AGPR. Round 3
// proved that holding even one extra value across the uh passes tips the
// allocator into scratch spill (553 MB HBM writes). Nothing may live across
// the uh boundary except what round 2 already kept.
__global__ __launch_bounds__(512, 4) void logits_mfma_kernel(
    const float* __restrict__ feat,          // [B,T,D] fp32
    const unsigned short* __restrict__ W1F,  // fragment-order bf16
    const float* __restrict__ ph,            // [B,U] biases folded
    const float* __restrict__ Vw,            // [U]
    float* __restrict__ lpart) {             // [16][B][T] partials
    __shared__ __align__(16) char As[65536];  // 16 panels x 64 rows x 64 B

    const int tid  = threadIdx.x;
    const int tt   = blockIdx.x;        // 0..15
    const int b    = blockIdx.y;
    const int t0   = tt * 64;
    const int lane = tid & 63;
    const int widx = tid >> 6;
    const int l31 = lane & 31, g = lane >> 5;

    // ---- stage A once: feat[b, t0..t0+64, :] fp32 -> bf16 swizzled panels ----
    {
        const int r  = tid >> 3;       // 0..63
        const int s0 = tid & 7;
        const float* src = feat + ((size_t)(b * T_ + t0 + r)) * D_;
        const int xr = (r >> 2) & 3;
#pragma unroll
        for (int i = 0; i < 8; ++i) {
            const int s = s0 + 8 * i;            // 16B slot in row
            const float4 v0 = *(const float4*)(src + s * 8);
            const float4 v1 = *(const float4*)(src + s * 8 + 4);
            uint4 w;
            w.x = f2bf_pk(v0.x, v0.y);
            w.y = f2bf_pk(v0.z, v0.w);
            w.z = f2bf_pk(v1.x, v1.y);
            w.w = f2bf_pk(v1.z, v1.w);
            const int panel = s >> 2, q = s & 3;
            *(uint4*)&As[panel * 4096 + r * 64 + (q ^ xr) * 16] = w;
        }
    }
    __syncthreads();   // the ONLY barrier in this kernel

    // B frag bases for the wave's u-strip in each u-half (u0 = uh*512+widx*64)
    const char* bb0 = (const char*)W1F + (size_t)(widx * 2) * 32768 + lane * 16;
    const char* bb1 = bb0 + (size_t)16 * 32768;

    f32x16 acc[2][2];
    bf16x8 b0[4], b1[4];

    auto loadB = [&](const char* bb, bf16x8* dst, int kt) {
#pragma unroll
        for (int nt = 0; nt < 2; ++nt)
#pragma unroll
            for (int ks = 0; ks < 2; ++ks)
                dst[nt * 2 + ks] =
                    *(const bf16x8*)(bb + nt * 32768 + (kt * 2 + ks) * 1024);
    };

    auto computeStep = [&](int kt, const bf16x8* bfr) {
        bf16x8 af[2][2];   // [ks][mt]
#pragma unroll
        for (int ks = 0; ks < 2; ++ks)
#pragma unroll
            for (int mt = 0; mt < 2; ++mt) {
                const int rr = mt * 32 + l31;
                const int q  = (2 * ks + g) ^ ((rr >> 2) & 3);
                af[ks][mt] = *(const bf16x8*)&As[kt * 4096 + rr * 64 + q * 16];
            }
        __builtin_amdgcn_s_setprio(1);
#pragma unroll
        for (int ks = 0; ks < 2; ++ks)
#pragma unroll
            for (int mt = 0; mt < 2; ++mt)
#pragma unroll
                for (int nt = 0; nt < 2; ++nt)
                    acc[mt][nt] = __builtin_amdgcn_mfma_f32_32x32x16_bf16(
                        af[ks][mt], bfr[nt * 2 + ks], acc[mt][nt], 0, 0, 0);
        __builtin_amdgcn_s_setprio(0);
    };

    loadB(bb0, b0, 0);
#pragma unroll
    for (int uh = 0; uh < 2; ++uh) {
        const char* bb = uh ? bb1 : bb0;
#pragma unroll
        for (int mt = 0; mt < 2; ++mt)
#pragma unroll
            for (int nt = 0; nt < 2; ++nt) acc[mt][nt] = (f32x16)(0.f);

        for (int kt = 0; kt < 16; kt += 2) {
            loadB(bb, b1, kt + 1);
            computeStep(kt, b0);
            if (kt + 2 < 16) loadB(bb, b0, kt + 2);
            computeStep(kt + 1, b1);
        }
        if (uh == 0) loadB(bb1, b0, 0);   // prefetch next pass under epilogue

        // ---- fused epilogue: tanh + V-dot into flat v[32] ----
        float v[32];
#pragma unroll
        for (int i = 0; i < 32; ++i) v[i] = 0.f;

#pragma unroll
        for (int nt = 0; nt < 2; ++nt) {
            const int u = uh * 512 + widx * 64 + nt * 32 + l31;
            const float phv = ph[b * U_ + u];
            const float vw  = Vw[u];
#pragma unroll
            for (int mt = 0; mt < 2; ++mt)
#pragma unroll
                for (int r = 0; r < 16; ++r)
                    v[mt * 16 + r] =
                        fmaf(vw, fast_tanh(acc[mt][nt][r] + phv), v[mt * 16 + r]);
        }

        // ---- multi-value tree reduce over the 32 lanes of each half ----
        // After 5 stages lane p holds the full u-strip sum for flat index
        // p&31 => row(p) = (p&3) + 8*((p>>2)&3) + 4*(p>>5) + 32*((p>>4)&1).
#pragma unroll
        for (int s = 0; s < 5; ++s) {
            const int pb = 1 << s;
            const bool hi = (l31 & pb) != 0;
#pragma unroll
            for (int j = 0; j < (16 >> s); ++j) {
                const float a = v[2 * j];
                const float c = v[2 * j + 1];
                const float keep = hi ? c : a;
                const float send = hi ? a : c;
                v[j] = keep + __shfl_xor(send, pb);
            }
        }

        // ---- identity-order gather + ONE ascending-contiguous 256 B store.
        // Dest lane r wants the value of lane p with row(p)=r:
        //   l31(p) = (r&3) | (((r>>3)&3)<<2) | (((r>>5)&1)<<4), g(p)=(r>>2)&1.
        const int src = ((lane & 3) | (((lane >> 3) & 3) << 2) |
                         (((lane >> 5) & 1) << 4)) + 32 * ((lane >> 2) & 1);
        const float out = __shfl(v[0], src);
        lpart[((size_t)(uh * 8 + widx)) * (B_ * T_) + (size_t)b * T_ + t0 +
              lane] = out;
    }
}

// K3: fused softmax + attn-write + context accumulation. grid (8 seg, B),
// block 512. Sums the 16 logit partial slots per t (stride B*T, coalesced,
// L2-hot), computes softmax, writes its own attn t-slice, then atomically
// accumulates its 128-t context contribution into out_ctx (zeroed by prep).
__global__ __launch_bounds__(512) void ctx_kernel(
    const float* __restrict__ feat, const float* __restrict__ lpart,
    float* __restrict__ attn, float* __restrict__ ctx_out) {
    const int b   = blockIdx.y;
    const int seg = blockIdx.x;
    const int tid = threadIdx.x;
    __shared__ float wls[1024];
    __shared__ float redm[8];
    __shared__ float reds[8];

    float v[2];
    float mx = -3.4e38f;
#pragma unroll
    for (int j = 0; j < 2; ++j) {
        const int t = b * T_ + tid + 512 * j;
        float s0 = 0.f, s1 = 0.f;
#pragma unroll
        for (int sl = 0; sl < 8; ++sl) {
            s0 += lpart[(size_t)(2 * sl) * (B_ * T_) + t];
            s1 += lpart[(size_t)(2 * sl + 1) * (B_ * T_) + t];
        }
        v[j] = s0 + s1;
        mx = fmaxf(mx, v[j]);
    }
#pragma unroll
    for (int off = 32; off > 0; off >>= 1) mx = fmaxf(mx, __shfl_xor(mx, off));
    if ((tid & 63) == 0) redm[tid >> 6] = mx;
    __syncthreads();
    mx = fmaxf(fmaxf(fmaxf(redm[0], redm[1]), fmaxf(redm[2], redm[3])),
               fmaxf(fmaxf(redm[4], redm[5]), fmaxf(redm[6], redm[7])));
    float s = 0.f;
#pragma unroll
    for (int j = 0; j < 2; ++j) {
        v[j] = __expf(v[j] - mx);
        s += v[j];
    }
#pragma unroll
    for (int off = 32; off > 0; off >>= 1) s += __shfl_xor(s, off);
    if ((tid & 63) == 0) reds[tid >> 6] = s;
    __syncthreads();
    s = ((reds[0] + reds[1]) + (reds[2] + reds[3])) +
        ((reds[4] + reds[5]) + (reds[6] + reds[7]));
    const float inv = 1.0f / s;
    wls[tid]       = v[0] * inv;
    wls[tid + 512] = v[1] * inv;
    __syncthreads();

    // attn write: own slice only
    if (tid < 128) attn[b * T_ + seg * 128 + tid] = wls[seg * 128 + tid];

    // context over this block's 128 t (4 quarters of 32 t)
    const int q  = tid >> 7;
    const int d4 = (tid & 127) * 4;
    const int t0 = seg * 128 + q * 32;
    const float* fb = feat + ((size_t)(b * T_ + t0)) * D_ + d4;
    const float* wb = &wls[t0];
    float4 acc = {0.f, 0.f, 0.f, 0.f};
#pragma unroll 4
    for (int t = 0; t < 32; ++t) {
        const float w  = wb[t];
        const float4 f = *(const float4*)&fb[(size_t)t * D_];
        acc.x = fmaf(w, f.x, acc.x);
        acc.y = fmaf(w, f.y, acc.y);
        acc.z = fmaf(w, f.z, acc.z);
        acc.w = fmaf(w, f.w, acc.w);
    }
    float* dst = ctx_out + b * D_ + d4;
    atomicAdd(dst + 0, acc.x);
    atomicAdd(dst + 1, acc.y);
    atomicAdd(dst + 2, acc.z);
    atomicAdd(dst + 3, acc.w);
}

extern "C" void kernel_launch(void* const* d_in, const int* in_sizes, int n_in,
                              void* d_out, int out_size, void* d_ws, size_t ws_size,
                              hipStream_t stream) {
    const float* feat   = (const float*)d_in[0];
    const float* hidden = (const float*)d_in[1];
    const float* W1w    = (const float*)d_in[2];
    const float* W1b    = (const float*)d_in[3];
    const float* W2w    = (const float*)d_in[4];
    const float* W2b    = (const float*)d_in[5];
    const float* Vw     = (const float*)d_in[6];
    // V_b cancels in softmax and doesn't affect context.

    float* out_ctx  = (float*)d_out;             // [B,D]
    float* out_attn = out_ctx + B_ * D_;         // [B,T]

    unsigned short* W1F = (unsigned short*)d_ws;             // U*D bf16 = 1 MB
    float* ph     = (float*)(W1F + (size_t)U_ * D_);         // B*U
    float* lpart  = ph + B_ * U_;                            // 16*B*T = 4 MB

    prep_kernel<<<512, 256, 0, stream>>>(W1w, hidden, W2w, W2b, W1b, W1F, ph,
                                         out_ctx);
    logits_mfma_kernel<<<dim3(16, B_), 512, 0, stream>>>(feat, W1F, ph, Vw,
                                                         lpart);
    ctx_kernel<<<dim3(8, B_), 512, 0, stream>>>(feat, lpart, out_attn, out_ctx);
}

// Round 5
// 326.209 us; speedup vs baseline: 1.5697x; 1.0552x over previous
//
#include <hip/hip_runtime.h>
#include <math.h>

#define B_ 64
#define T_ 1024
#define D_ 512
#define U_ 1024

typedef __bf16 bf16x8 __attribute__((ext_vector_type(8)));
typedef float f32x16 __attribute__((ext_vector_type(16)));
typedef unsigned int u32;

__device__ __forceinline__ float fast_tanh(float x) {
    float ax = fabsf(x);
    float e = __expf(2.0f * ax);
    float r = 1.0f - __fdividef(2.0f, e + 1.0f);
    return copysignf(r, x);
}

__device__ __forceinline__ u32 f2bf_pk(float lo, float hi) {
    u32 a = __float_as_uint(lo) + 0x8000u;
    u32 b = __float_as_uint(hi) + 0x8000u;
    return (a >> 16) | (b & 0xffff0000u);
}

// K_prep: blocks [0,256): W1 [D][U] fp32 -> W1F in MFMA-fragment order:
//   frag=(ut*16+kt)*2+ks holds B-frag for u-tile ut (32 u), k=kt*32+ks*16;
//   slot (frag,lane) = 8 bf16: u=ut*32+(lane&31), k0=kt*32+ks*16+(lane>>5)*8.
// blocks [256,512): ph[b][u] = hidden·W2 + W2_b + W1_b; also zero out_ctx
// for the atomic accumulation in ctx_kernel.
__global__ __launch_bounds__(256) void prep_kernel(
    const float* __restrict__ W1, const float* __restrict__ hidden,
    const float* __restrict__ W2, const float* __restrict__ W2b,
    const float* __restrict__ W1b,
    unsigned short* __restrict__ W1F, float* __restrict__ ph,
    float* __restrict__ ctx0) {
    if (blockIdx.x < 256) {
        const int gid  = blockIdx.x * 256 + threadIdx.x;  // 0..65535
        const int lane = gid & 63;
        const int frag = gid >> 6;                        // 0..1023
        const int ks = frag & 1;
        const int kt = (frag >> 1) & 15;
        const int ut = frag >> 5;
        const int u  = ut * 32 + (lane & 31);
        const int k0 = kt * 32 + ks * 16 + (lane >> 5) * 8;
        float f[8];
#pragma unroll
        for (int j = 0; j < 8; ++j) f[j] = W1[(size_t)(k0 + j) * U_ + u];
        uint4 w;
        w.x = f2bf_pk(f[0], f[1]);
        w.y = f2bf_pk(f[2], f[3]);
        w.z = f2bf_pk(f[4], f[5]);
        w.w = f2bf_pk(f[6], f[7]);
        *(uint4*)&W1F[(size_t)gid * 8] = w;
    } else {
        const int bx = blockIdx.x - 256;
        const int zi = bx * 256 + (int)threadIdx.x;
        if (zi < B_ * D_) ctx0[zi] = 0.f;
        const int u  = (bx & 3) * 256 + threadIdx.x;
        const int b  = bx >> 2;
        const float* h = hidden + b * D_;
        float acc = 0.f;
#pragma unroll 8
        for (int d = 0; d < D_; ++d) acc = fmaf(h[d], W2[(size_t)d * U_ + u], acc);
        ph[b * U_ + u] = acc + W2b[u] + W1b[u];
    }
}

// K2: fused bf16 32x32x16-MFMA GEMM + tanh + V-dot.
// v5 = round-0 GRID (one uh per block, 2048 blocks, 8/CU: the kernel is
// latency-bound — r0's 2048-block grid measured FASTER than the 1024-block
// sequential-uh variant despite duplicated staging) + round-4 EPILOGUE
// (register shfl tree + identity-order gather + one ascending-contiguous
// 256 B store per wave; r0's 2-barrier LDS-scratch epilogue removed).
// ONE barrier. Register liveness is a strict subset of round 2's (fits the
// 128-reg/wave budget at launch_bounds(512,4) — see round-3 spill lesson).
__global__ __launch_bounds__(512, 4) void logits_mfma_kernel(
    const float* __restrict__ feat,          // [B,T,D] fp32
    const unsigned short* __restrict__ W1F,  // fragment-order bf16
    const float* __restrict__ ph,            // [B,U] biases folded
    const float* __restrict__ Vw,            // [U]
    float* __restrict__ lpart) {             // [16][B][T] partials
    __shared__ __align__(16) char As[65536];  // 16 panels x 64 rows x 64 B

    const int tid  = threadIdx.x;
    const int gx   = blockIdx.x;        // uh fastest: A-sharing pair co-dispatch
    const int uh   = gx & 1;
    const int tt   = gx >> 1;
    const int b    = blockIdx.y;
    const int t0   = tt * 64;
    const int lane = tid & 63;
    const int widx = tid >> 6;
    const int l31 = lane & 31, g = lane >> 5;

    // ---- stage A once: feat[b, t0..t0+64, :] fp32 -> bf16 swizzled panels ----
    {
        const int r  = tid >> 3;       // 0..63
        const int s0 = tid & 7;
        const float* src = feat + ((size_t)(b * T_ + t0 + r)) * D_;
        const int xr = (r >> 2) & 3;
#pragma unroll
        for (int i = 0; i < 8; ++i) {
            const int s = s0 + 8 * i;            // 16B slot in row
            const float4 v0 = *(const float4*)(src + s * 8);
            const float4 v1 = *(const float4*)(src + s * 8 + 4);
            uint4 w;
            w.x = f2bf_pk(v0.x, v0.y);
            w.y = f2bf_pk(v0.z, v0.w);
            w.z = f2bf_pk(v1.x, v1.y);
            w.w = f2bf_pk(v1.z, v1.w);
            const int panel = s >> 2, q = s & 3;
            *(uint4*)&As[panel * 4096 + r * 64 + (q ^ xr) * 16] = w;
        }
    }
    __syncthreads();   // the ONLY barrier in this kernel

    // B frag base for the wave's u-strip: u0 = uh*512 + widx*64
    const char* bfbase = (const char*)W1F +
                         (size_t)((uh * 16 + widx * 2)) * 32768 + lane * 16;

    f32x16 acc[2][2];
    bf16x8 b0[4], b1[4];

    auto loadB = [&](bf16x8* dst, int kt) {
#pragma unroll
        for (int nt = 0; nt < 2; ++nt)
#pragma unroll
            for (int ks = 0; ks < 2; ++ks)
                dst[nt * 2 + ks] =
                    *(const bf16x8*)(bfbase + nt * 32768 + (kt * 2 + ks) * 1024);
    };

    auto computeStep = [&](int kt, const bf16x8* bfr) {
        bf16x8 af[2][2];   // [ks][mt]
#pragma unroll
        for (int ks = 0; ks < 2; ++ks)
#pragma unroll
            for (int mt = 0; mt < 2; ++mt) {
                const int rr = mt * 32 + l31;
                const int q  = (2 * ks + g) ^ ((rr >> 2) & 3);
                af[ks][mt] = *(const bf16x8*)&As[kt * 4096 + rr * 64 + q * 16];
            }
        __builtin_amdgcn_s_setprio(1);
#pragma unroll
        for (int ks = 0; ks < 2; ++ks)
#pragma unroll
            for (int mt = 0; mt < 2; ++mt)
#pragma unroll
                for (int nt = 0; nt < 2; ++nt)
                    acc[mt][nt] = __builtin_amdgcn_mfma_f32_32x32x16_bf16(
                        af[ks][mt], bfr[nt * 2 + ks], acc[mt][nt], 0, 0, 0);
        __builtin_amdgcn_s_setprio(0);
    };

#pragma unroll
    for (int mt = 0; mt < 2; ++mt)
#pragma unroll
        for (int nt = 0; nt < 2; ++nt) acc[mt][nt] = (f32x16)(0.f);

    loadB(b0, 0);
    for (int kt = 0; kt < 16; kt += 2) {
        loadB(b1, kt + 1);
        computeStep(kt, b0);
        if (kt + 2 < 16) loadB(b0, kt + 2);
        computeStep(kt + 1, b1);
    }

    // ---- fused epilogue: tanh + V-dot into flat v[32] ----
    float v[32];
#pragma unroll
    for (int i = 0; i < 32; ++i) v[i] = 0.f;

#pragma unroll
    for (int nt = 0; nt < 2; ++nt) {
        const int u = uh * 512 + widx * 64 + nt * 32 + l31;
        const float phv = ph[b * U_ + u];
        const float vw  = Vw[u];
#pragma unroll
        for (int mt = 0; mt < 2; ++mt)
#pragma unroll
            for (int r = 0; r < 16; ++r)
                v[mt * 16 + r] =
                    fmaf(vw, fast_tanh(acc[mt][nt][r] + phv), v[mt * 16 + r]);
    }

    // ---- multi-value tree reduce over the 32 lanes of each half ----
    // After 5 stages lane p holds the full u-strip sum for flat index
    // p&31 => row(p) = (p&3) + 8*((p>>2)&3) + 4*(p>>5) + 32*((p>>4)&1).
#pragma unroll
    for (int s = 0; s < 5; ++s) {
        const int pb = 1 << s;
        const bool hi = (l31 & pb) != 0;
#pragma unroll
        for (int j = 0; j < (16 >> s); ++j) {
            const float a = v[2 * j];
            const float c = v[2 * j + 1];
            const float keep = hi ? c : a;
            const float send = hi ? a : c;
            v[j] = keep + __shfl_xor(send, pb);
        }
    }

    // ---- identity-order gather + ONE ascending-contiguous 256 B store.
    // Dest lane r wants the value of lane p with row(p)=r:
    //   l31(p) = (r&3) | (((r>>3)&3)<<2) | (((r>>5)&1)<<4), g(p)=(r>>2)&1.
    const int src = ((lane & 3) | (((lane >> 3) & 3) << 2) |
                     (((lane >> 5) & 1) << 4)) + 32 * ((lane >> 2) & 1);
    const float out = __shfl(v[0], src);
    lpart[((size_t)(uh * 8 + widx)) * (B_ * T_) + (size_t)b * T_ + t0 + lane] =
        out;
}

// K3: fused softmax + attn-write + context accumulation. grid (8 seg, B),
// block 512. Sums the 16 logit partial slots per t (stride B*T, coalesced,
// L2-hot), computes softmax, writes its own attn t-slice, then accumulates
// its 128-t context partial. v5: the 4 q-group float4 partials are reduced
// through LDS first, so only 128 threads issue atomics (4x fewer atomic ops).
__global__ __launch_bounds__(512) void ctx_kernel(
    const float* __restrict__ feat, const float* __restrict__ lpart,
    float* __restrict__ attn, float* __restrict__ ctx_out) {
    const int b   = blockIdx.y;
    const int seg = blockIdx.x;
    const int tid = threadIdx.x;
    __shared__ float wls[1024];
    __shared__ float redm[8];
    __shared__ float reds[8];
    __shared__ __align__(16) float4 cp[512];

    float v[2];
    float mx = -3.4e38f;
#pragma unroll
    for (int j = 0; j < 2; ++j) {
        const int t = b * T_ + tid + 512 * j;
        float s0 = 0.f, s1 = 0.f;
#pragma unroll
        for (int sl = 0; sl < 8; ++sl) {
            s0 += lpart[(size_t)(2 * sl) * (B_ * T_) + t];
            s1 += lpart[(size_t)(2 * sl + 1) * (B_ * T_) + t];
        }
        v[j] = s0 + s1;
        mx = fmaxf(mx, v[j]);
    }
#pragma unroll
    for (int off = 32; off > 0; off >>= 1) mx = fmaxf(mx, __shfl_xor(mx, off));
    if ((tid & 63) == 0) redm[tid >> 6] = mx;
    __syncthreads();
    mx = fmaxf(fmaxf(fmaxf(redm[0], redm[1]), fmaxf(redm[2], redm[3])),
               fmaxf(fmaxf(redm[4], redm[5]), fmaxf(redm[6], redm[7])));
    float s = 0.f;
#pragma unroll
    for (int j = 0; j < 2; ++j) {
        v[j] = __expf(v[j] - mx);
        s += v[j];
    }
#pragma unroll
    for (int off = 32; off > 0; off >>= 1) s += __shfl_xor(s, off);
    if ((tid & 63) == 0) reds[tid >> 6] = s;
    __syncthreads();
    s = ((reds[0] + reds[1]) + (reds[2] + reds[3])) +
        ((reds[4] + reds[5]) + (reds[6] + reds[7]));
    const float inv = 1.0f / s;
    wls[tid]       = v[0] * inv;
    wls[tid + 512] = v[1] * inv;
    __syncthreads();

    // attn write: own slice only
    if (tid < 128) attn[b * T_ + seg * 128 + tid] = wls[seg * 128 + tid];

    // context over this block's 128 t (4 quarters of 32 t)
    const int q  = tid >> 7;
    const int d4 = (tid & 127) * 4;
    const int t0 = seg * 128 + q * 32;
    const float* fb = feat + ((size_t)(b * T_ + t0)) * D_ + d4;
    const float* wb = &wls[t0];
    float4 acc = {0.f, 0.f, 0.f, 0.f};
#pragma unroll 4
    for (int t = 0; t < 32; ++t) {
        const float w  = wb[t];
        const float4 f = *(const float4*)&fb[(size_t)t * D_];
        acc.x = fmaf(w, f.x, acc.x);
        acc.y = fmaf(w, f.y, acc.y);
        acc.z = fmaf(w, f.z, acc.z);
        acc.w = fmaf(w, f.w, acc.w);
    }
    cp[tid] = acc;
    __syncthreads();
    if (tid < 128) {
        const float4 a0 = cp[tid];
        const float4 a1 = cp[tid + 128];
        const float4 a2 = cp[tid + 256];
        const float4 a3 = cp[tid + 384];
        float* dst = ctx_out + b * D_ + tid * 4;
        atomicAdd(dst + 0, (a0.x + a1.x) + (a2.x + a3.x));
        atomicAdd(dst + 1, (a0.y + a1.y) + (a2.y + a3.y));
        atomicAdd(dst + 2, (a0.z + a1.z) + (a2.z + a3.z));
        atomicAdd(dst + 3, (a0.w + a1.w) + (a2.w + a3.w));
    }
}

extern "C" void kernel_launch(void* const* d_in, const int* in_sizes, int n_in,
                              void* d_out, int out_size, void* d_ws, size_t ws_size,
                              hipStream_t stream) {
    const float* feat   = (const float*)d_in[0];
    const float* hidden = (const float*)d_in[1];
    const float* W1w    = (const float*)d_in[2];
    const float* W1b    = (const float*)d_in[3];
    const float* W2w    = (const float*)d_in[4];
    const float* W2b    = (const float*)d_in[5];
    const float* Vw     = (const float*)d_in[6];
    // V_b cancels in softmax and doesn't affect context.

    float* out_ctx  = (float*)d_out;             // [B,D]
    float* out_attn = out_ctx + B_ * D_;         // [B,T]

    unsigned short* W1F = (unsigned short*)d_ws;             // U*D bf16 = 1 MB
    float* ph     = (float*)(W1F + (size_t)U_ * D_);         // B*U
    float* lpart  = ph + B_ * U_;                            // 16*B*T = 4 MB

    prep_kernel<<<512, 256, 0, stream>>>(W1w, hidden, W2w, W2b, W1b, W1F, ph,
                                         out_ctx);
    logits_mfma_kernel<<<dim3(32, B_), 512, 0, stream>>>(feat, W1F, ph, Vw,
                                                         lpart);
    ctx_kernel<<<dim3(8, B_), 512, 0, stream>>>(feat, lpart, out_attn, out_ctx);
}

// Round 6
// 318.402 us; speedup vs baseline: 1.6082x; 1.0245x over previous
//
#include <hip/hip_runtime.h>
#include <math.h>

#define B_ 64
#define T_ 1024
#define D_ 512
#define U_ 1024

typedef __bf16 bf16x8 __attribute__((ext_vector_type(8)));
typedef float f32x16 __attribute__((ext_vector_type(16)));
typedef unsigned int u32;

// tanh(x) given x2 = 2x, pre-clamped: 1 - 2/(1+e^{x2}). Sign-correct for both
// tails (x2->-inf: 1-2=-1; x2->+inf: 1-0=+1); clamp +-18 bounds e^{x2} and
// keeps tanh exact to <1e-7. 3 VALU + 2 trans vs the old abs/copysign form's
// 7 VALU + 2 trans.
__device__ __forceinline__ float tanh_from_x2(float x2) {
    const float xc = __builtin_amdgcn_fmed3f(x2, -18.f, 18.f);
    const float e  = __expf(xc);
    const float r  = __builtin_amdgcn_rcpf(e + 1.0f);
    return fmaf(-2.0f, r, 1.0f);
}

// pack two f32 -> two bf16 (round-half-up): 2 adds + 1 v_perm
// result = (bits(lo)+0x8000)>>16 | ((bits(hi)+0x8000) & 0xffff0000)
__device__ __forceinline__ u32 f2bf_pk(float lo, float hi) {
    u32 a = __float_as_uint(lo) + 0x8000u;
    u32 b = __float_as_uint(hi) + 0x8000u;
    return __builtin_amdgcn_perm(b, a, 0x07060302u);
}

// K_prep: blocks [0,256): W1 [D][U] fp32 -> W1F in MFMA-fragment order:
//   frag=(ut*16+kt)*2+ks holds B-frag for u-tile ut (32 u), k=kt*32+ks*16;
//   slot (frag,lane) = 8 bf16: u=ut*32+(lane&31), k0=kt*32+ks*16+(lane>>5)*8.
// blocks [256,512): ph[b][u] = hidden·W2 + W2_b + W1_b; also zero out_ctx
// for the atomic accumulation in ctx_kernel.
__global__ __launch_bounds__(256) void prep_kernel(
    const float* __restrict__ W1, const float* __restrict__ hidden,
    const float* __restrict__ W2, const float* __restrict__ W2b,
    const float* __restrict__ W1b,
    unsigned short* __restrict__ W1F, float* __restrict__ ph,
    float* __restrict__ ctx0) {
    if (blockIdx.x < 256) {
        const int gid  = blockIdx.x * 256 + threadIdx.x;  // 0..65535
        const int lane = gid & 63;
        const int frag = gid >> 6;                        // 0..1023
        const int ks = frag & 1;
        const int kt = (frag >> 1) & 15;
        const int ut = frag >> 5;
        const int u  = ut * 32 + (lane & 31);
        const int k0 = kt * 32 + ks * 16 + (lane >> 5) * 8;
        float f[8];
#pragma unroll
        for (int j = 0; j < 8; ++j) f[j] = W1[(size_t)(k0 + j) * U_ + u];
        uint4 w;
        w.x = f2bf_pk(f[0], f[1]);
        w.y = f2bf_pk(f[2], f[3]);
        w.z = f2bf_pk(f[4], f[5]);
        w.w = f2bf_pk(f[6], f[7]);
        *(uint4*)&W1F[(size_t)gid * 8] = w;
    } else {
        const int bx = blockIdx.x - 256;
        const int zi = bx * 256 + (int)threadIdx.x;
        if (zi < B_ * D_) ctx0[zi] = 0.f;
        const int u  = (bx & 3) * 256 + threadIdx.x;
        const int b  = bx >> 2;
        const float* h = hidden + b * D_;
        float acc = 0.f;
#pragma unroll 8
        for (int d = 0; d < D_; ++d) acc = fmaf(h[d], W2[(size_t)d * U_ + u], acc);
        ph[b * U_ + u] = acc + W2b[u] + W1b[u];
    }
}

// K2: fused bf16 32x32x16-MFMA GEMM + tanh + V-dot.
// Structure (proven r5): one uh per block, 2048 blocks (latency-bound regime —
// the 2048-block grid beats 1024-block sequential-uh despite duplicated
// staging); ONE barrier; register shfl-tree epilogue + identity-order gather +
// one ascending-contiguous 256 B store per wave. Register budget: 64 VGPR +
// 64 AGPR = exactly the 128/wave cap at launch_bounds(512,4) — round 3 proved
// +1 live value across phases spills to scratch (553 MB HBM). v6: slimmed
// epilogue VALU — clamped-tanh (5 VALU + 2 trans per elem vs 9+2) and v_perm
// bf16 pack in staging (3 ops vs 5).
__global__ __launch_bounds__(512, 4) void logits_mfma_kernel(
    const float* __restrict__ feat,          // [B,T,D] fp32
    const unsigned short* __restrict__ W1F,  // fragment-order bf16
    const float* __restrict__ ph,            // [B,U] biases folded
    const float* __restrict__ Vw,            // [U]
    float* __restrict__ lpart) {             // [16][B][T] partials
    __shared__ __align__(16) char As[65536];  // 16 panels x 64 rows x 64 B

    const int tid  = threadIdx.x;
    const int gx   = blockIdx.x;        // uh fastest: A-sharing pair co-dispatch
    const int uh   = gx & 1;
    const int tt   = gx >> 1;
    const int b    = blockIdx.y;
    const int t0   = tt * 64;
    const int lane = tid & 63;
    const int widx = tid >> 6;
    const int l31 = lane & 31, g = lane >> 5;

    // ---- stage A once: feat[b, t0..t0+64, :] fp32 -> bf16 swizzled panels ----
    {
        const int r  = tid >> 3;       // 0..63
        const int s0 = tid & 7;
        const float* src = feat + ((size_t)(b * T_ + t0 + r)) * D_;
        const int xr = (r >> 2) & 3;
#pragma unroll
        for (int i = 0; i < 8; ++i) {
            const int s = s0 + 8 * i;            // 16B slot in row
            const float4 v0 = *(const float4*)(src + s * 8);
            const float4 v1 = *(const float4*)(src + s * 8 + 4);
            uint4 w;
            w.x = f2bf_pk(v0.x, v0.y);
            w.y = f2bf_pk(v0.z, v0.w);
            w.z = f2bf_pk(v1.x, v1.y);
            w.w = f2bf_pk(v1.z, v1.w);
            const int panel = s >> 2, q = s & 3;
            *(uint4*)&As[panel * 4096 + r * 64 + (q ^ xr) * 16] = w;
        }
    }
    __syncthreads();   // the ONLY barrier in this kernel

    // B frag base for the wave's u-strip: u0 = uh*512 + widx*64
    const char* bfbase = (const char*)W1F +
                         (size_t)((uh * 16 + widx * 2)) * 32768 + lane * 16;

    f32x16 acc[2][2];
    bf16x8 b0[4], b1[4];

    auto loadB = [&](bf16x8* dst, int kt) {
#pragma unroll
        for (int nt = 0; nt < 2; ++nt)
#pragma unroll
            for (int ks = 0; ks < 2; ++ks)
                dst[nt * 2 + ks] =
                    *(const bf16x8*)(bfbase + nt * 32768 + (kt * 2 + ks) * 1024);
    };

    auto computeStep = [&](int kt, const bf16x8* bfr) {
        bf16x8 af[2][2];   // [ks][mt]
#pragma unroll
        for (int ks = 0; ks < 2; ++ks)
#pragma unroll
            for (int mt = 0; mt < 2; ++mt) {
                const int rr = mt * 32 + l31;
                const int q  = (2 * ks + g) ^ ((rr >> 2) & 3);
                af[ks][mt] = *(const bf16x8*)&As[kt * 4096 + rr * 64 + q * 16];
            }
        __builtin_amdgcn_s_setprio(1);
#pragma unroll
        for (int ks = 0; ks < 2; ++ks)
#pragma unroll
            for (int mt = 0; mt < 2; ++mt)
#pragma unroll
                for (int nt = 0; nt < 2; ++nt)
                    acc[mt][nt] = __builtin_amdgcn_mfma_f32_32x32x16_bf16(
                        af[ks][mt], bfr[nt * 2 + ks], acc[mt][nt], 0, 0, 0);
        __builtin_amdgcn_s_setprio(0);
    };

#pragma unroll
    for (int mt = 0; mt < 2; ++mt)
#pragma unroll
        for (int nt = 0; nt < 2; ++nt) acc[mt][nt] = (f32x16)(0.f);

    loadB(b0, 0);
    for (int kt = 0; kt < 16; kt += 2) {
        loadB(b1, kt + 1);
        computeStep(kt, b0);
        if (kt + 2 < 16) loadB(b0, kt + 2);
        computeStep(kt + 1, b1);
    }

    // ---- fused epilogue: tanh + V-dot into flat v[32] ----
    // x2 = 2*(acc+phv) via one fmaf with hoisted phv2; clamped-tanh form.
    float v[32];
#pragma unroll
    for (int i = 0; i < 32; ++i) v[i] = 0.f;

#pragma unroll
    for (int nt = 0; nt < 2; ++nt) {
        const int u = uh * 512 + widx * 64 + nt * 32 + l31;
        const float phv2 = 2.0f * ph[b * U_ + u];
        const float vw   = Vw[u];
#pragma unroll
        for (int mt = 0; mt < 2; ++mt)
#pragma unroll
            for (int r = 0; r < 16; ++r) {
                const float th =
                    tanh_from_x2(fmaf(2.0f, acc[mt][nt][r], phv2));
                v[mt * 16 + r] = fmaf(vw, th, v[mt * 16 + r]);
            }
    }

    // ---- multi-value tree reduce over the 32 lanes of each half ----
    // After 5 stages lane p holds the full u-strip sum for flat index
    // p&31 => row(p) = (p&3) + 8*((p>>2)&3) + 4*(p>>5) + 32*((p>>4)&1).
#pragma unroll
    for (int s = 0; s < 5; ++s) {
        const int pb = 1 << s;
        const bool hi = (l31 & pb) != 0;
#pragma unroll
        for (int j = 0; j < (16 >> s); ++j) {
            const float a = v[2 * j];
            const float c = v[2 * j + 1];
            const float keep = hi ? c : a;
            const float send = hi ? a : c;
            v[j] = keep + __shfl_xor(send, pb);
        }
    }

    // ---- identity-order gather + ONE ascending-contiguous 256 B store.
    // Dest lane r wants the value of lane p with row(p)=r:
    //   l31(p) = (r&3) | (((r>>3)&3)<<2) | (((r>>5)&1)<<4), g(p)=(r>>2)&1.
    const int src = ((lane & 3) | (((lane >> 3) & 3) << 2) |
                     (((lane >> 5) & 1) << 4)) + 32 * ((lane >> 2) & 1);
    const float out = __shfl(v[0], src);
    lpart[((size_t)(uh * 8 + widx)) * (B_ * T_) + (size_t)b * T_ + t0 + lane] =
        out;
}

// K3: fused softmax + attn-write + context accumulation. grid (8 seg, B),
// block 512 (r4's exact form — measured best; r5's LDS pre-reduce of atomics
// regressed). Sums the 16 logit partial slots per t (stride B*T, coalesced,
// L2-hot), computes softmax, writes its own attn t-slice, then atomically
// accumulates its 128-t context contribution into out_ctx (zeroed by prep).
__global__ __launch_bounds__(512) void ctx_kernel(
    const float* __restrict__ feat, const float* __restrict__ lpart,
    float* __restrict__ attn, float* __restrict__ ctx_out) {
    const int b   = blockIdx.y;
    const int seg = blockIdx.x;
    const int tid = threadIdx.x;
    __shared__ float wls[1024];
    __shared__ float redm[8];
    __shared__ float reds[8];

    float v[2];
    float mx = -3.4e38f;
#pragma unroll
    for (int j = 0; j < 2; ++j) {
        const int t = b * T_ + tid + 512 * j;
        float s0 = 0.f, s1 = 0.f;
#pragma unroll
        for (int sl = 0; sl < 8; ++sl) {
            s0 += lpart[(size_t)(2 * sl) * (B_ * T_) + t];
            s1 += lpart[(size_t)(2 * sl + 1) * (B_ * T_) + t];
        }
        v[j] = s0 + s1;
        mx = fmaxf(mx, v[j]);
    }
#pragma unroll
    for (int off = 32; off > 0; off >>= 1) mx = fmaxf(mx, __shfl_xor(mx, off));
    if ((tid & 63) == 0) redm[tid >> 6] = mx;
    __syncthreads();
    mx = fmaxf(fmaxf(fmaxf(redm[0], redm[1]), fmaxf(redm[2], redm[3])),
               fmaxf(fmaxf(redm[4], redm[5]), fmaxf(redm[6], redm[7])));
    float s = 0.f;
#pragma unroll
    for (int j = 0; j < 2; ++j) {
        v[j] = __expf(v[j] - mx);
        s += v[j];
    }
#pragma unroll
    for (int off = 32; off > 0; off >>= 1) s += __shfl_xor(s, off);
    if ((tid & 63) == 0) reds[tid >> 6] = s;
    __syncthreads();
    s = ((reds[0] + reds[1]) + (reds[2] + reds[3])) +
        ((reds[4] + reds[5]) + (reds[6] + reds[7]));
    const float inv = 1.0f / s;
    wls[tid]       = v[0] * inv;
    wls[tid + 512] = v[1] * inv;
    __syncthreads();

    // attn write: own slice only
    if (tid < 128) attn[b * T_ + seg * 128 + tid] = wls[seg * 128 + tid];

    // context over this block's 128 t (4 quarters of 32 t)
    const int q  = tid >> 7;
    const int d4 = (tid & 127) * 4;
    const int t0 = seg * 128 + q * 32;
    const float* fb = feat + ((size_t)(b * T_ + t0)) * D_ + d4;
    const float* wb = &wls[t0];
    float4 acc = {0.f, 0.f, 0.f, 0.f};
#pragma unroll 4
    for (int t = 0; t < 32; ++t) {
        const float w  = wb[t];
        const float4 f = *(const float4*)&fb[(size_t)t * D_];
        acc.x = fmaf(w, f.x, acc.x);
        acc.y = fmaf(w, f.y, acc.y);
        acc.z = fmaf(w, f.z, acc.z);
        acc.w = fmaf(w, f.w, acc.w);
    }
    float* dst = ctx_out + b * D_ + d4;
    atomicAdd(dst + 0, acc.x);
    atomicAdd(dst + 1, acc.y);
    atomicAdd(dst + 2, acc.z);
    atomicAdd(dst + 3, acc.w);
}

extern "C" void kernel_launch(void* const* d_in, const int* in_sizes, int n_in,
                              void* d_out, int out_size, void* d_ws, size_t ws_size,
                              hipStream_t stream) {
    const float* feat   = (const float*)d_in[0];
    const float* hidden = (const float*)d_in[1];
    const float* W1w    = (const float*)d_in[2];
    const float* W1b    = (const float*)d_in[3];
    const float* W2w    = (const float*)d_in[4];
    const float* W2b    = (const float*)d_in[5];
    const float* Vw     = (const float*)d_in[6];
    // V_b cancels in softmax and doesn't affect context.

    float* out_ctx  = (float*)d_out;             // [B,D]
    float* out_attn = out_ctx + B_ * D_;         // [B,T]

    unsigned short* W1F = (unsigned short*)d_ws;             // U*D bf16 = 1 MB
    float* ph     = (float*)(W1F + (size_t)U_ * D_);         // B*U
    float* lpart  = ph + B_ * U_;                            // 16*B*T = 4 MB

    prep_kernel<<<512, 256, 0, stream>>>(W1w, hidden, W2w, W2b, W1b, W1F, ph,
                                         out_ctx);
    logits_mfma_kernel<<<dim3(32, B_), 512, 0, stream>>>(feat, W1F, ph, Vw,
                                                         lpart);
    ctx_kernel<<<dim3(8, B_), 512, 0, stream>>>(feat, lpart, out_attn, out_ctx);
}

// Round 7
// 312.106 us; speedup vs baseline: 1.6406x; 1.0202x over previous
//
#include <hip/hip_runtime.h>
#include <math.h>

#define B_ 64
#define T_ 1024
#define D_ 512
#define U_ 1024

typedef __bf16 bf16x8 __attribute__((ext_vector_type(8)));
typedef float f32x16 __attribute__((ext_vector_type(16)));
typedef unsigned int u32;

// tanh(x) given x2 = 2x, pre-clamped: 1 - 2/(1+e^{x2}). Sign-correct for both
// tails; clamp +-18 keeps tanh exact to <1e-7. 3 VALU + 2 trans.
__device__ __forceinline__ float tanh_from_x2(float x2) {
    const float xc = __builtin_amdgcn_fmed3f(x2, -18.f, 18.f);
    const float e  = __expf(xc);
    const float r  = __builtin_amdgcn_rcpf(e + 1.0f);
    return fmaf(-2.0f, r, 1.0f);
}

// pack two f32 -> two bf16 (round-half-up): 2 adds + 1 v_perm
__device__ __forceinline__ u32 f2bf_pk(float lo, float hi) {
    u32 a = __float_as_uint(lo) + 0x8000u;
    u32 b = __float_as_uint(hi) + 0x8000u;
    return __builtin_amdgcn_perm(b, a, 0x07060302u);
}

// K_prep: blocks [0,256): W1 [D][U] fp32 -> W1F in MFMA-fragment order:
//   frag=(ut*16+kt)*2+ks holds B-frag for u-tile ut (32 u), k=kt*32+ks*16;
//   slot (frag,lane) = 8 bf16: u=ut*32+(lane&31), k0=kt*32+ks*16+(lane>>5)*8.
// blocks [256,512): ph[b][u] = hidden·W2 + W2_b + W1_b; also zero out_ctx
// for the atomic accumulation in ctx_kernel.
__global__ __launch_bounds__(256) void prep_kernel(
    const float* __restrict__ W1, const float* __restrict__ hidden,
    const float* __restrict__ W2, const float* __restrict__ W2b,
    const float* __restrict__ W1b,
    unsigned short* __restrict__ W1F, float* __restrict__ ph,
    float* __restrict__ ctx0) {
    if (blockIdx.x < 256) {
        const int gid  = blockIdx.x * 256 + threadIdx.x;  // 0..65535
        const int lane = gid & 63;
        const int frag = gid >> 6;                        // 0..1023
        const int ks = frag & 1;
        const int kt = (frag >> 1) & 15;
        const int ut = frag >> 5;
        const int u  = ut * 32 + (lane & 31);
        const int k0 = kt * 32 + ks * 16 + (lane >> 5) * 8;
        float f[8];
#pragma unroll
        for (int j = 0; j < 8; ++j) f[j] = W1[(size_t)(k0 + j) * U_ + u];
        uint4 w;
        w.x = f2bf_pk(f[0], f[1]);
        w.y = f2bf_pk(f[2], f[3]);
        w.z = f2bf_pk(f[4], f[5]);
        w.w = f2bf_pk(f[6], f[7]);
        *(uint4*)&W1F[(size_t)gid * 8] = w;
    } else {
        const int bx = blockIdx.x - 256;
        const int zi = bx * 256 + (int)threadIdx.x;
        if (zi < B_ * D_) ctx0[zi] = 0.f;
        const int u  = (bx & 3) * 256 + threadIdx.x;
        const int b  = bx >> 2;
        const float* h = hidden + b * D_;
        float acc = 0.f;
#pragma unroll 8
        for (int d = 0; d < D_; ++d) acc = fmaf(h[d], W2[(size_t)d * U_ + u], acc);
        ph[b * U_ + u] = acc + W2b[u] + W1b[u];
    }
}

// K2: fused bf16 32x32x16-MFMA GEMM + tanh + V-dot.
// v7: thread-coarsened 2x in N. Same 2048-block grid / 64t x 512u tile as r6,
// but 4 waves x (64t x 128u, nt=4) instead of 8 waves x 64u. Rationale: the
// LDS read pipe was the widest per-block cost (all waves re-read the same A
// rows; 8x64KB -> 4x64KB halves it), and per-kt MFMA runs double (16) for
// more ILP per lgkm wait. acc = 128 AGPR -> 256-reg class (8 waves/CU;
// launch_bounds(256,2)). Peak est ~233 unified regs — 18 below the cliff;
// r3 lesson: a spill shows as WRITE_SIZE explosion.
// ONE barrier; register shfl-tree epilogue + identity-order gather + one
// ascending-contiguous 256 B store per wave.
__global__ __launch_bounds__(256, 2) void logits_mfma_kernel(
    const float* __restrict__ feat,          // [B,T,D] fp32
    const unsigned short* __restrict__ W1F,  // fragment-order bf16
    const float* __restrict__ ph,            // [B,U] biases folded
    const float* __restrict__ Vw,            // [U]
    float* __restrict__ lpart) {             // [8][B][T] partials
    __shared__ __align__(16) char As[65536];  // 16 panels x 64 rows x 64 B

    const int tid  = threadIdx.x;
    const int gx   = blockIdx.x;        // uh fastest: A-sharing pair co-dispatch
    const int uh   = gx & 1;
    const int tt   = gx >> 1;
    const int b    = blockIdx.y;
    const int t0   = tt * 64;
    const int lane = tid & 63;
    const int widx = tid >> 6;          // 0..3
    const int l31 = lane & 31, g = lane >> 5;

    // ---- stage A once: feat[b, t0..t0+64, :] fp32 -> bf16 swizzled panels ----
    // 256 threads: each covers one row (r) x 16 of the 64 16B-slots.
    {
        const int r  = tid >> 2;       // 0..63
        const int s0 = tid & 3;
        const float* src = feat + ((size_t)(b * T_ + t0 + r)) * D_;
        const int xr = (r >> 2) & 3;
#pragma unroll
        for (int i = 0; i < 16; ++i) {
            const int s = s0 + 4 * i;            // 16B slot in row
            const float4 v0 = *(const float4*)(src + s * 8);
            const float4 v1 = *(const float4*)(src + s * 8 + 4);
            uint4 w;
            w.x = f2bf_pk(v0.x, v0.y);
            w.y = f2bf_pk(v0.z, v0.w);
            w.z = f2bf_pk(v1.x, v1.y);
            w.w = f2bf_pk(v1.z, v1.w);
            const int panel = s >> 2, q = s & 3;
            *(uint4*)&As[panel * 4096 + r * 64 + (q ^ xr) * 16] = w;
        }
    }
    __syncthreads();   // the ONLY barrier in this kernel

    // B frag base for the wave's u-strip: u0 = uh*512 + widx*128 (4 u-tiles)
    const char* bfbase = (const char*)W1F +
                         (size_t)((uh * 16 + widx * 4)) * 32768 + lane * 16;

    f32x16 acc[2][4];
    bf16x8 b0[8], b1[8];

    auto loadB = [&](bf16x8* dst, int kt) {
#pragma unroll
        for (int nt = 0; nt < 4; ++nt)
#pragma unroll
            for (int ks = 0; ks < 2; ++ks)
                dst[nt * 2 + ks] =
                    *(const bf16x8*)(bfbase + nt * 32768 + (kt * 2 + ks) * 1024);
    };

    auto computeStep = [&](int kt, const bf16x8* bfr) {
        bf16x8 af[2][2];   // [ks][mt]
#pragma unroll
        for (int ks = 0; ks < 2; ++ks)
#pragma unroll
            for (int mt = 0; mt < 2; ++mt) {
                const int rr = mt * 32 + l31;
                const int q  = (2 * ks + g) ^ ((rr >> 2) & 3);
                af[ks][mt] = *(const bf16x8*)&As[kt * 4096 + rr * 64 + q * 16];
            }
        __builtin_amdgcn_s_setprio(1);
#pragma unroll
        for (int ks = 0; ks < 2; ++ks)
#pragma unroll
            for (int mt = 0; mt < 2; ++mt)
#pragma unroll
                for (int nt = 0; nt < 4; ++nt)
                    acc[mt][nt] = __builtin_amdgcn_mfma_f32_32x32x16_bf16(
                        af[ks][mt], bfr[nt * 2 + ks], acc[mt][nt], 0, 0, 0);
        __builtin_amdgcn_s_setprio(0);
    };

#pragma unroll
    for (int mt = 0; mt < 2; ++mt)
#pragma unroll
        for (int nt = 0; nt < 4; ++nt) acc[mt][nt] = (f32x16)(0.f);

    loadB(b0, 0);
    for (int kt = 0; kt < 16; kt += 2) {
        loadB(b1, kt + 1);
        computeStep(kt, b0);
        if (kt + 2 < 16) loadB(b0, kt + 2);
        computeStep(kt + 1, b1);
    }

    // ---- fused epilogue: tanh + V-dot into flat v[32] ----
    float v[32];
#pragma unroll
    for (int i = 0; i < 32; ++i) v[i] = 0.f;

#pragma unroll
    for (int nt = 0; nt < 4; ++nt) {
        const int u = uh * 512 + widx * 128 + nt * 32 + l31;
        const float phv2 = 2.0f * ph[b * U_ + u];
        const float vw   = Vw[u];
#pragma unroll
        for (int mt = 0; mt < 2; ++mt)
#pragma unroll
            for (int r = 0; r < 16; ++r) {
                const float th =
                    tanh_from_x2(fmaf(2.0f, acc[mt][nt][r], phv2));
                v[mt * 16 + r] = fmaf(vw, th, v[mt * 16 + r]);
            }
    }

    // ---- multi-value tree reduce over the 32 lanes of each half ----
    // After 5 stages lane p holds the full u-strip sum for flat index
    // p&31 => row(p) = (p&3) + 8*((p>>2)&3) + 4*(p>>5) + 32*((p>>4)&1).
#pragma unroll
    for (int s = 0; s < 5; ++s) {
        const int pb = 1 << s;
        const bool hi = (l31 & pb) != 0;
#pragma unroll
        for (int j = 0; j < (16 >> s); ++j) {
            const float a = v[2 * j];
            const float c = v[2 * j + 1];
            const float keep = hi ? c : a;
            const float send = hi ? a : c;
            v[j] = keep + __shfl_xor(send, pb);
        }
    }

    // ---- identity-order gather + ONE ascending-contiguous 256 B store.
    // Dest lane r wants the value of lane p with row(p)=r:
    //   l31(p) = (r&3) | (((r>>3)&3)<<2) | (((r>>5)&1)<<4), g(p)=(r>>2)&1.
    const int src = ((lane & 3) | (((lane >> 3) & 3) << 2) |
                     (((lane >> 5) & 1) << 4)) + 32 * ((lane >> 2) & 1);
    const float out = __shfl(v[0], src);
    lpart[((size_t)(uh * 4 + widx)) * (B_ * T_) + (size_t)b * T_ + t0 + lane] =
        out;
}

// K3: fused softmax + attn-write + context accumulation. grid (8 seg, B),
// block 512 (r4's proven form). Sums the 8 logit partial slots per t (stride
// B*T, coalesced, L2-hot), computes softmax, writes its own attn t-slice,
// then atomically accumulates its 128-t context contribution into out_ctx.
__global__ __launch_bounds__(512) void ctx_kernel(
    const float* __restrict__ feat, const float* __restrict__ lpart,
    float* __restrict__ attn, float* __restrict__ ctx_out) {
    const int b   = blockIdx.y;
    const int seg = blockIdx.x;
    const int tid = threadIdx.x;
    __shared__ float wls[1024];
    __shared__ float redm[8];
    __shared__ float reds[8];

    float v[2];
    float mx = -3.4e38f;
#pragma unroll
    for (int j = 0; j < 2; ++j) {
        const int t = b * T_ + tid + 512 * j;
        float s0 = 0.f, s1 = 0.f;
#pragma unroll
        for (int sl = 0; sl < 4; ++sl) {
            s0 += lpart[(size_t)(2 * sl) * (B_ * T_) + t];
            s1 += lpart[(size_t)(2 * sl + 1) * (B_ * T_) + t];
        }
        v[j] = s0 + s1;
        mx = fmaxf(mx, v[j]);
    }
#pragma unroll
    for (int off = 32; off > 0; off >>= 1) mx = fmaxf(mx, __shfl_xor(mx, off));
    if ((tid & 63) == 0) redm[tid >> 6] = mx;
    __syncthreads();
    mx = fmaxf(fmaxf(fmaxf(redm[0], redm[1]), fmaxf(redm[2], redm[3])),
               fmaxf(fmaxf(redm[4], redm[5]), fmaxf(redm[6], redm[7])));
    float s = 0.f;
#pragma unroll
    for (int j = 0; j < 2; ++j) {
        v[j] = __expf(v[j] - mx);
        s += v[j];
    }
#pragma unroll
    for (int off = 32; off > 0; off >>= 1) s += __shfl_xor(s, off);
    if ((tid & 63) == 0) reds[tid >> 6] = s;
    __syncthreads();
    s = ((reds[0] + reds[1]) + (reds[2] + reds[3])) +
        ((reds[4] + reds[5]) + (reds[6] + reds[7]));
    const float inv = 1.0f / s;
    wls[tid]       = v[0] * inv;
    wls[tid + 512] = v[1] * inv;
    __syncthreads();

    // attn write: own slice only
    if (tid < 128) attn[b * T_ + seg * 128 + tid] = wls[seg * 128 + tid];

    // context over this block's 128 t (4 quarters of 32 t)
    const int q  = tid >> 7;
    const int d4 = (tid & 127) * 4;
    const int t0 = seg * 128 + q * 32;
    const float* fb = feat + ((size_t)(b * T_ + t0)) * D_ + d4;
    const float* wb = &wls[t0];
    float4 acc = {0.f, 0.f, 0.f, 0.f};
#pragma unroll 4
    for (int t = 0; t < 32; ++t) {
        const float w  = wb[t];
        const float4 f = *(const float4*)&fb[(size_t)t * D_];
        acc.x = fmaf(w, f.x, acc.x);
        acc.y = fmaf(w, f.y, acc.y);
        acc.z = fmaf(w, f.z, acc.z);
        acc.w = fmaf(w, f.w, acc.w);
    }
    float* dst = ctx_out + b * D_ + d4;
    atomicAdd(dst + 0, acc.x);
    atomicAdd(dst + 1, acc.y);
    atomicAdd(dst + 2, acc.z);
    atomicAdd(dst + 3, acc.w);
}

extern "C" void kernel_launch(void* const* d_in, const int* in_sizes, int n_in,
                              void* d_out, int out_size, void* d_ws, size_t ws_size,
                              hipStream_t stream) {
    const float* feat   = (const float*)d_in[0];
    const float* hidden = (const float*)d_in[1];
    const float* W1w    = (const float*)d_in[2];
    const float* W1b    = (const float*)d_in[3];
    const float* W2w    = (const float*)d_in[4];
    const float* W2b    = (const float*)d_in[5];
    const float* Vw     = (const float*)d_in[6];
    // V_b cancels in softmax and doesn't affect context.

    float* out_ctx  = (float*)d_out;             // [B,D]
    float* out_attn = out_ctx + B_ * D_;         // [B,T]

    unsigned short* W1F = (unsigned short*)d_ws;             // U*D bf16 = 1 MB
    float* ph     = (float*)(W1F + (size_t)U_ * D_);         // B*U
    float* lpart  = ph + B_ * U_;                            // 8*B*T = 2 MB

    prep_kernel<<<512, 256, 0, stream>>>(W1w, hidden, W2w, W2b, W1b, W1F, ph,
                                         out_ctx);
    logits_mfma_kernel<<<dim3(32, B_), 256, 0, stream>>>(feat, W1F, ph, Vw,
                                                         lpart);
    ctx_kernel<<<dim3(8, B_), 512, 0, stream>>>(feat, lpart, out_attn, out_ctx);
}